// Round 3
// baseline (36815.747 us; speedup 1.0000x reference)
//
#include <hip/hip_runtime.h>
#include <math.h>

// Problem constants (V,E,H,K,T,B) = (32000, 512, 512, 32, 256, 64)
#define T_STEPS 256
#define BATCH   64
#define HID     512
#define EMB     512
#define KTAGS   32
#define NEGV    -100000.0f
#define START_TAG 30
#define END_TAG   31

#define NBLK      256   // persistent blocks (must all be co-resident)
#define NBLK_DIR  128   // blocks per direction

// ---------------------------------------------------------------------------
// Zero the barrier counters + output scalar.
// ---------------------------------------------------------------------------
__global__ __launch_bounds__(256) void init_zero(unsigned int* __restrict__ bars,
                                                 float* __restrict__ out)
{
    int i = blockIdx.x * 256 + threadIdx.x;
    if (i < 2048) bars[i] = 0u;
    if (i == 0) *out = 0.0f;
}

// ---------------------------------------------------------------------------
// Persistent BiLSTM: one launch, both layers, all 256 timesteps.
// Grid: 256 blocks x 256 threads. bid>>7 = direction, (bid&127)*4 = 4 h-cols
// owned (=> 16 gate rows). Waves split K 4 ways; lane tile 4 batch x 4 gates;
// partials reduced via LDS (Gred). c-state: one register per thread.
// Cross-block sync: monotonic per-(layer,dir,step) counters (no reset), with
// agent-scope release/acquire atomics + threadfence. The x@Wih part of step s
// is computed BEFORE waiting on h(s-1) to hide barrier latency.
// Weight slices are block-static => XCD-L2-resident all 512 iterations.
// ---------------------------------------------------------------------------
__global__ __launch_bounds__(256) void lstm_persistent(
    const int*   __restrict__ tokens,  // [T][B]
    const float* __restrict__ embed,   // [V][EMB]
    const float* __restrict__ wih0, const float* __restrict__ whh0, const float* __restrict__ bb0,
    const float* __restrict__ wih1, const float* __restrict__ whh1, const float* __restrict__ bb1,
    float* __restrict__ hs0,           // [T][B][1024]
    float* __restrict__ hs1,           // [T][B][1024]
    unsigned int* __restrict__ bars)   // [2][2][256] step counters + [1024] layer
{
    // LDS: 33,792 + 10,240 + 16,384 = 60,416 B  (<= 80KB => 2 blocks/CU capacity)
    __shared__ __align__(16) float As[4][64][33];   // per-wave A tile [b][k], pad33: 2-way max
    __shared__ __align__(16) float Ws[4][32][20];   // per-wave W tile [k][gc], b128-aligned rows
    __shared__ __align__(16) float Gred[4][16][64]; // per-wave partial gates [gc][b]

    const int bid  = blockIdx.x;
    const int d    = bid >> 7;           // direction
    const int nc4  = (bid & 127) * 4;    // first owned h-col
    const int tid  = threadIdx.x;
    const int w    = tid >> 6;           // wave id (K-split)
    const int lane = tid & 63;
    const int bq   = lane & 15;          // batch quad: rows 4*bq..+3
    const int cq   = lane >> 4;          // gate g = cq; cols j=0..3
    const int rb   = tid >> 2;           // reduce-phase batch row
    const int rj   = tid & 3;            // reduce-phase h-col offset

    float creg = 0.0f;                   // cell state for (rb, nc4+rj)

    for (int l = 0; l < 2; ++l) {
        const int xK = l ? 1024 : 512;
        const float* wih = (l ? wih1 : wih0) + (long long)d * 2048 * xK;
        const float* whh = (l ? whh1 : whh0) + (long long)d * 2048 * HID;
        const float* bia = (l ? bb1 : bb0) + (long long)d * 2048;
        const float* xs  = l ? hs0 : (const float*)0;
        float* ho        = l ? hs1 : hs0;
        unsigned int* barsl = bars + l * 512 + d * 256;

        float breg[4];
        #pragma unroll
        for (int g = 0; g < 4; ++g) breg[g] = bia[g * HID + nc4 + rj];
        creg = 0.0f;

        const int kwX    = xK >> 2;      // per-wave K span (input phase)
        const int tilesX = kwX >> 5;     // 32-k tiles per wave

        for (int s = 0; s < T_STEPS; ++s) {
            const int tt    = d ? (T_STEPS - 1 - s) : s;
            const int tprev = d ? (tt + 1) : (tt - 1);

            float acc[4][4];
            #pragma unroll
            for (int i = 0; i < 4; ++i)
                #pragma unroll
                for (int j = 0; j < 4; ++j) acc[i][j] = 0.0f;

            int tokv = 0;
            if (!l) tokv = tokens[tt * BATCH + lane];

            // ---------------- X phase: g += x_t @ Wih^T  (no h dependency) --
            for (int t4 = 0; t4 < tilesX; ++t4) {
                const int k0 = w * kwX + t4 * 32;
                #pragma unroll
                for (int it = 0; it < 8; ++it) {           // A: 64 rows x 32 k
                    const int idx = lane + 64 * it;
                    const int row = idx >> 3, q = idx & 7;
                    const float* src;
                    if (!l) src = embed + (long long)__shfl(tokv, row) * EMB;
                    else    src = xs + ((long long)tt * BATCH + row) * 1024;
                    const float4 v = *(const float4*)(src + k0 + 4 * q);
                    As[w][row][4*q+0] = v.x; As[w][row][4*q+1] = v.y;
                    As[w][row][4*q+2] = v.z; As[w][row][4*q+3] = v.w;
                }
                #pragma unroll
                for (int it = 0; it < 2; ++it) {           // W: 16 gc x 32 k
                    const int idx = lane + 64 * it;
                    const int c = idx >> 3, q = idx & 7;
                    const int r = (c >> 2) * HID + nc4 + (c & 3);
                    const float4 v = *(const float4*)(wih + (long long)r * xK + k0 + 4 * q);
                    Ws[w][4*q+0][c] = v.x; Ws[w][4*q+1][c] = v.y;
                    Ws[w][4*q+2][c] = v.z; Ws[w][4*q+3][c] = v.w;
                }
                #pragma unroll 8
                for (int kk = 0; kk < 32; ++kk) {
                    const float a0 = As[w][4*bq+0][kk];
                    const float a1 = As[w][4*bq+1][kk];
                    const float a2 = As[w][4*bq+2][kk];
                    const float a3 = As[w][4*bq+3][kk];
                    const float4 wv = *(const float4*)&Ws[w][kk][4*cq];
                    acc[0][0]+=a0*wv.x; acc[0][1]+=a0*wv.y; acc[0][2]+=a0*wv.z; acc[0][3]+=a0*wv.w;
                    acc[1][0]+=a1*wv.x; acc[1][1]+=a1*wv.y; acc[1][2]+=a1*wv.z; acc[1][3]+=a1*wv.w;
                    acc[2][0]+=a2*wv.x; acc[2][1]+=a2*wv.y; acc[2][2]+=a2*wv.z; acc[2][3]+=a2*wv.w;
                    acc[3][0]+=a3*wv.x; acc[3][1]+=a3*wv.y; acc[3][2]+=a3*wv.z; acc[3][3]+=a3*wv.w;
                }
            }

            // ---------------- wait for h(s-1), then H phase -----------------
            if (s > 0) {
                if (tid == 0) {
                    long t_spin = 0;
                    while (__hip_atomic_load(&barsl[s-1], __ATOMIC_ACQUIRE,
                                             __HIP_MEMORY_SCOPE_AGENT) < NBLK_DIR) {
                        __builtin_amdgcn_s_sleep(2);
                        if (++t_spin > (1L << 27)) break;  // pathology -> visible failure, not hang
                    }
                }
                __syncthreads();
                __threadfence();
                const float* hp = ho + (long long)tprev * (BATCH * 1024) + d * HID;
                for (int t4 = 0; t4 < 4; ++t4) {
                    const int k0 = w * 128 + t4 * 32;
                    #pragma unroll
                    for (int it = 0; it < 8; ++it) {
                        const int idx = lane + 64 * it;
                        const int row = idx >> 3, q = idx & 7;
                        const float4 v = *(const float4*)(hp + (long long)row * 1024 + k0 + 4 * q);
                        As[w][row][4*q+0] = v.x; As[w][row][4*q+1] = v.y;
                        As[w][row][4*q+2] = v.z; As[w][row][4*q+3] = v.w;
                    }
                    #pragma unroll
                    for (int it = 0; it < 2; ++it) {
                        const int idx = lane + 64 * it;
                        const int c = idx >> 3, q = idx & 7;
                        const int r = (c >> 2) * HID + nc4 + (c & 3);
                        const float4 v = *(const float4*)(whh + (long long)r * HID + k0 + 4 * q);
                        Ws[w][4*q+0][c] = v.x; Ws[w][4*q+1][c] = v.y;
                        Ws[w][4*q+2][c] = v.z; Ws[w][4*q+3][c] = v.w;
                    }
                    #pragma unroll 8
                    for (int kk = 0; kk < 32; ++kk) {
                        const float a0 = As[w][4*bq+0][kk];
                        const float a1 = As[w][4*bq+1][kk];
                        const float a2 = As[w][4*bq+2][kk];
                        const float a3 = As[w][4*bq+3][kk];
                        const float4 wv = *(const float4*)&Ws[w][kk][4*cq];
                        acc[0][0]+=a0*wv.x; acc[0][1]+=a0*wv.y; acc[0][2]+=a0*wv.z; acc[0][3]+=a0*wv.w;
                        acc[1][0]+=a1*wv.x; acc[1][1]+=a1*wv.y; acc[1][2]+=a1*wv.z; acc[1][3]+=a1*wv.w;
                        acc[2][0]+=a2*wv.x; acc[2][1]+=a2*wv.y; acc[2][2]+=a2*wv.z; acc[2][3]+=a2*wv.w;
                        acc[3][0]+=a3*wv.x; acc[3][1]+=a3*wv.y; acc[3][2]+=a3*wv.z; acc[3][3]+=a3*wv.w;
                    }
                }
            }

            // ---------------- cross-wave reduce + gates + h write -----------
            #pragma unroll
            for (int i = 0; i < 4; ++i)
                #pragma unroll
                for (int j = 0; j < 4; ++j)
                    Gred[w][4*cq + j][4*bq + i] = acc[i][j];   // [gc][b]: 2-way max
            __syncthreads();

            float vg[4];
            #pragma unroll
            for (int g = 0; g < 4; ++g)
                vg[g] = breg[g] + Gred[0][4*g+rj][rb] + Gred[1][4*g+rj][rb]
                                + Gred[2][4*g+rj][rb] + Gred[3][4*g+rj][rb];
            const float si = 1.0f / (1.0f + __expf(-vg[0]));
            const float sf = 1.0f / (1.0f + __expf(-vg[1]));
            const float so = 1.0f / (1.0f + __expf(-vg[3]));
            const float cn = sf * creg + si * tanhf(vg[2]);
            const float hn = so * tanhf(cn);
            creg = cn;
            ho[((long long)tt * BATCH + rb) * 1024 + d * HID + nc4 + rj] = hn;

            __threadfence();     // publish h stores to agent scope
            __syncthreads();     // all threads' stores fenced; Gred reads done
            if (tid == 0)
                __hip_atomic_fetch_add(&barsl[s], 1u, __ATOMIC_RELEASE,
                                       __HIP_MEMORY_SCOPE_AGENT);
        }

        // ---------------- full barrier between layers -----------------------
        if (l == 0) {
            if (tid == 0) {
                __hip_atomic_fetch_add(&bars[1024], 1u, __ATOMIC_ACQ_REL,
                                       __HIP_MEMORY_SCOPE_AGENT);
                long t_spin = 0;
                while (__hip_atomic_load(&bars[1024], __ATOMIC_ACQUIRE,
                                         __HIP_MEMORY_SCOPE_AGENT) < NBLK) {
                    __builtin_amdgcn_s_sleep(2);
                    if (++t_spin > (1L << 27)) break;
                }
            }
            __syncthreads();
            __threadfence();
        }
    }
}

// ---------------------------------------------------------------------------
// feats = hs1 @ lin_w^T + lin_b   (64-row tiles, N=32 guarded)
// ---------------------------------------------------------------------------
__global__ __launch_bounds__(256) void gemm_feats(
    const float* __restrict__ A, long long lda,
    const float* __restrict__ W,      // [N][K]
    const float* __restrict__ bias,
    float* __restrict__ C,
    int M, int N, int K)
{
    __shared__ __align__(16) float As[64][34];
    __shared__ __align__(16) float Ws[32][68];

    const int m0 = blockIdx.y * 64;
    const int tid = threadIdx.x;
    const int tr = tid >> 4;
    const int tc = tid & 15;

    float acc[4][4];
    #pragma unroll
    for (int i = 0; i < 4; ++i)
        #pragma unroll
        for (int j = 0; j < 4; ++j) acc[i][j] = 0.0f;

    for (int k0 = 0; k0 < K; k0 += 32) {
        int idx = tid;
        #pragma unroll
        for (int it = 0; it < 2; ++it) {
            int row = idx >> 3;
            int q   = idx & 7;
            float4 v = *(const float4*)(A + (long long)(m0 + row) * lda + k0 + 4*q);
            As[row][4*q+0] = v.x; As[row][4*q+1] = v.y;
            As[row][4*q+2] = v.z; As[row][4*q+3] = v.w;
            idx += 256;
        }
        idx = tid;
        #pragma unroll
        for (int it = 0; it < 2; ++it) {
            int row = idx >> 3;
            int q   = idx & 7;
            float4 v = make_float4(0.f, 0.f, 0.f, 0.f);
            if (row < N)
                v = *(const float4*)(W + (long long)row * K + k0 + 4*q);
            Ws[4*q+0][row] = v.x; Ws[4*q+1][row] = v.y;
            Ws[4*q+2][row] = v.z; Ws[4*q+3][row] = v.w;
            idx += 256;
        }
        __syncthreads();
        #pragma unroll 8
        for (int kk = 0; kk < 32; ++kk) {
            float a0 = As[4*tr+0][kk], a1 = As[4*tr+1][kk];
            float a2 = As[4*tr+2][kk], a3 = As[4*tr+3][kk];
            float4 wv = *(const float4*)&Ws[kk][4*tc];
            acc[0][0] += a0*wv.x; acc[0][1] += a0*wv.y; acc[0][2] += a0*wv.z; acc[0][3] += a0*wv.w;
            acc[1][0] += a1*wv.x; acc[1][1] += a1*wv.y; acc[1][2] += a1*wv.z; acc[1][3] += a1*wv.w;
            acc[2][0] += a2*wv.x; acc[2][1] += a2*wv.y; acc[2][2] += a2*wv.z; acc[2][3] += a2*wv.w;
            acc[3][0] += a3*wv.x; acc[3][1] += a3*wv.y; acc[3][2] += a3*wv.z; acc[3][3] += a3*wv.w;
        }
        __syncthreads();
    }
    #pragma unroll
    for (int i = 0; i < 4; ++i) {
        int m = m0 + 4*tr + i;
        #pragma unroll
        for (int j = 0; j < 4; ++j) {
            int n = 4*tc + j;
            if (n < N) C[(long long)m * N + n] = acc[i][j] + bias[n];
        }
    }
}

// ---------------------------------------------------------------------------
// CRF: forward logsumexp scan + log_z + gold score + loss, one block per b.
// ---------------------------------------------------------------------------
__global__ __launch_bounds__(1024) void crf_kernel(
    const float* __restrict__ feats,   // [T*B][K]
    const float* __restrict__ trans,   // [K][K]
    const int*   __restrict__ tokens,  // [T*B]
    const int*   __restrict__ tags,    // [T*B]
    const int*   __restrict__ lengths, // [B]
    float* __restrict__ out)
{
    const int b = blockIdx.x;
    const int tid = threadIdx.x;
    __shared__ float tr_s[KTAGS*KTAGS];
    __shared__ float score_s[KTAGS];
    __shared__ float emit_s[KTAGS];
    __shared__ float red_s[16];
    __shared__ float logz_s;

    tr_s[tid] = trans[tid];            // 1024 == 32*32 exactly
    if (tid < KTAGS) score_s[tid] = (tid == START_TAG) ? 0.0f : NEGV;
    __syncthreads();

    const int i = tid >> 5, j = tid & 31;
    for (int t = 0; t < T_STEPS; ++t) {
        if (tid < KTAGS) emit_s[tid] = feats[((long long)t*BATCH + b)*KTAGS + tid];
        __syncthreads();
        float e = score_s[j] + tr_s[i*KTAGS + j];
        float m = e;
        m = fmaxf(m, __shfl_xor(m, 1));  m = fmaxf(m, __shfl_xor(m, 2));
        m = fmaxf(m, __shfl_xor(m, 4));  m = fmaxf(m, __shfl_xor(m, 8));
        m = fmaxf(m, __shfl_xor(m, 16));
        float p = __expf(e - m);
        p += __shfl_xor(p, 1); p += __shfl_xor(p, 2); p += __shfl_xor(p, 4);
        p += __shfl_xor(p, 8); p += __shfl_xor(p, 16);
        float nv = m + __logf(p) + emit_s[i];
        int msk = tokens[(long long)t*BATCH + b] > 0;
        __syncthreads();
        if (j == 0) score_s[i] = msk ? nv : score_s[i];
        __syncthreads();
    }

    if (tid < KTAGS) {
        float v = score_s[tid] + tr_s[END_TAG*KTAGS + tid];
        float m = v;
        m = fmaxf(m, __shfl_xor(m, 1));  m = fmaxf(m, __shfl_xor(m, 2));
        m = fmaxf(m, __shfl_xor(m, 4));  m = fmaxf(m, __shfl_xor(m, 8));
        m = fmaxf(m, __shfl_xor(m, 16));
        float p = __expf(v - m);
        p += __shfl_xor(p, 1); p += __shfl_xor(p, 2); p += __shfl_xor(p, 4);
        p += __shfl_xor(p, 8); p += __shfl_xor(p, 16);
        if (tid == 0) logz_s = m + __logf(p);
    }
    __syncthreads();

    float val = 0.0f;
    if (tid < T_STEPS) {
        int t = tid;
        int cur  = tags[(long long)t*BATCH + b];
        int prev = (t == 0) ? START_TAG : tags[(long long)(t-1)*BATCH + b];
        int msk  = tokens[(long long)t*BATCH + b] > 0;
        if (msk) val = tr_s[cur*KTAGS + prev]
                     + feats[((long long)t*BATCH + b)*KTAGS + cur];
    }
    val += __shfl_xor(val, 1);  val += __shfl_xor(val, 2);
    val += __shfl_xor(val, 4);  val += __shfl_xor(val, 8);
    val += __shfl_xor(val, 16); val += __shfl_xor(val, 32);
    int wave = tid >> 6, lane = tid & 63;
    if (lane == 0) red_s[wave] = val;
    __syncthreads();
    if (tid == 0) {
        float g = 0.0f;
        #pragma unroll
        for (int w = 0; w < 16; ++w) g += red_s[w];
        g += tr_s[END_TAG*KTAGS + tags[(long long)(T_STEPS-1)*BATCH + b]];
        atomicAdd(out, (logz_s - g) / (float)lengths[b]);
    }
}

// ---------------------------------------------------------------------------
extern "C" void kernel_launch(void* const* d_in, const int* in_sizes, int n_in,
                              void* d_out, int out_size, void* d_ws, size_t ws_size,
                              hipStream_t stream) {
    const int*   tokens  = (const int*)  d_in[0];
    const int*   tags    = (const int*)  d_in[1];
    const int*   lengths = (const int*)  d_in[2];
    const float* embed   = (const float*)d_in[3];
    const float* wih0    = (const float*)d_in[4];
    const float* whh0    = (const float*)d_in[5];
    const float* b0      = (const float*)d_in[6];
    const float* wih1    = (const float*)d_in[7];
    const float* whh1    = (const float*)d_in[8];
    const float* b1      = (const float*)d_in[9];
    const float* lin_w   = (const float*)d_in[10];
    const float* lin_b   = (const float*)d_in[11];
    const float* trans   = (const float*)d_in[12];

    // Workspace (~130 MiB): hs0, hs1, feats, barrier counters
    char*  ws    = (char*)d_ws;
    float* hs0   = (float*)(ws);                        // 16384*1024*4 = 67108864
    float* hs1   = (float*)(ws + 67108864ULL);          //                67108864
    float* feats = (float*)(ws + 134217728ULL);         // 16384*32*4   =  2097152
    unsigned int* bars = (unsigned int*)(ws + 136314880ULL); // 8192 B

    float* out = (float*)d_out;

    init_zero<<<dim3(8), 256, 0, stream>>>(bars, out);

    lstm_persistent<<<dim3(NBLK), 256, 0, stream>>>(
        tokens, embed, wih0, whh0, b0, wih1, whh1, b1, hs0, hs1, bars);

    gemm_feats<<<dim3(1, 256, 1), 256, 0, stream>>>(
        hs1, (long long)(2*HID), lin_w, lin_b, feats,
        T_STEPS*BATCH, KTAGS, 2*HID);

    crf_kernel<<<dim3(BATCH), 1024, 0, stream>>>(feats, trans, tokens, tags,
                                                 lengths, out);
}

// Round 4
// 4908.839 us; speedup vs baseline: 7.4999x; 7.4999x over previous
//
#include <hip/hip_runtime.h>
#include <math.h>

// Problem constants (V,E,H,K,T,B) = (32000, 512, 512, 32, 256, 64)
#define T_STEPS 256
#define BATCH   64
#define HID     512
#define EMB     512
#define KTAGS   32
#define NEGV    -100000.0f
#define START_TAG 30
#define END_TAG   31

#define NBLK      256
#define NBLK_DIR  128
#define SPIN_LIM  (1 << 26)

typedef __attribute__((ext_vector_type(8))) short short8;
typedef __attribute__((ext_vector_type(4))) float f32x4;

union V16 { uint4 u; short8 s; };
union HQ  { unsigned long long q[2]; short8 s; };

static __device__ __forceinline__ unsigned short f2b(float f) {
    unsigned u = __float_as_uint(f);
    return (unsigned short)((u + 0x7fffu + ((u >> 16) & 1u)) >> 16);
}
static __device__ __forceinline__ float b2f(unsigned short us) {
    return __uint_as_float(((unsigned)us) << 16);
}

// ---------------------------------------------------------------------------
// Init: zero flags (IF-coherent stores — step kernel reads them via agent
// atomics which bypass L2, so normal stores would be invisible) + d_out.
// ---------------------------------------------------------------------------
__global__ __launch_bounds__(256) void init_zero(unsigned int* __restrict__ flags,
                                                 float* __restrict__ out)
{
    int i = blockIdx.x * 256 + threadIdx.x;
    if (i < 1028)
        __hip_atomic_store(flags + i, 0u, __ATOMIC_RELAXED, __HIP_MEMORY_SCOPE_AGENT);
    if (i == 0)
        __hip_atomic_store(out, 0.0f, __ATOMIC_RELAXED, __HIP_MEMORY_SCOPE_AGENT);
}

// ---------------------------------------------------------------------------
// embed fp32 -> bf16 (one-time, 16.4M elements)
// ---------------------------------------------------------------------------
__global__ __launch_bounds__(256) void convert_embed(const float* __restrict__ src,
                                                     unsigned short* __restrict__ dst)
{
    long long i = ((long long)blockIdx.x * 256 + threadIdx.x) * 4;
    if (i >= (long long)32000 * 512) return;
    float4 v = *(const float4*)(src + i);
    ushort4 o;
    o.x = f2b(v.x); o.y = f2b(v.y); o.z = f2b(v.z); o.w = f2b(v.w);
    *(ushort4*)(dst + i) = o;
}

// ---------------------------------------------------------------------------
// Pack Wih|Whh (fp32) into bf16 MFMA B-fragment stream.
// Stream: [d][nt(128)][kt(KT=xKt+16)][lane(64)][j(8)], where the 16 B-frag
// cols of block nt are {g*512 + nt*4 + j2 : g=0..3, j2=0..3} (c = g*4+j2 =
// lane&15), and k_local = (lane>>4)*8 + j.  kt<xKt -> Wih, else Whh.
// Thread t == flat destination fragment index => perfectly coalesced stores.
// ---------------------------------------------------------------------------
__global__ __launch_bounds__(256) void pack_w(const float* __restrict__ wih,
                                              const float* __restrict__ whh,
                                              int xK,
                                              unsigned short* __restrict__ wpack)
{
    const int xKt = xK >> 5, KT = xKt + 16;
    long long t = (long long)blockIdx.x * 256 + threadIdx.x;
    if (t >= (long long)2 * 128 * KT * 64) return;
    int lane = (int)(t & 63);
    long long rest = t >> 6;
    int kt = (int)(rest % KT); rest /= KT;
    int nt = (int)(rest % 128);
    int d  = (int)(rest / 128);
    int c = lane & 15, q = lane >> 4;
    int r = (c >> 2) * 512 + nt * 4 + (c & 3);
    const float* src;
    if (kt < xKt) src = wih + ((long long)d * 2048 * xK + (long long)r * xK + kt * 32 + q * 8);
    else          src = whh + ((long long)d * 2048 * 512 + (long long)r * 512 + (kt - xKt) * 32 + q * 8);
    float4 v0 = *(const float4*)src;
    float4 v1 = *(const float4*)(src + 4);
    unsigned short o[8] = { f2b(v0.x), f2b(v0.y), f2b(v0.z), f2b(v0.w),
                            f2b(v1.x), f2b(v1.y), f2b(v1.z), f2b(v1.w) };
    *(uint4*)(wpack + t * 8) = *(const uint4*)o;
}

// ---------------------------------------------------------------------------
// Persistent BiLSTM, MFMA edition.
// 256 blocks x 256 thr. d=bid>>7; block owns 4 h-cols (nt*4..+3) => 16 gate
// cols (4 per gate). 4 waves split K. Inner loop: B-frag = 1 coalesced
// dwordx4 from L2-resident packed weights; A-frag = 1 dwordx4 from global
// bf16 rows (embed/hs0) or 2 relaxed-agent u64 atomics (h_prev via IF).
// NO LDS in the GEMM loop, NO fences in the step loop — weights stay in L2.
// Sync: relaxed agent atomics on IF-homed counters; s_waitcnt vmcnt(0)
// orders h stores before the flag add. h double-buffered by step parity.
// ---------------------------------------------------------------------------
__global__ __launch_bounds__(256) void lstm_mfma(
    const int* __restrict__ tokens,
    const unsigned short* __restrict__ embB,   // [32000][512] bf16
    const unsigned short* __restrict__ wp0,    // packed L0 weights
    const unsigned short* __restrict__ wp1,    // packed L1 weights
    const float* __restrict__ bb0, const float* __restrict__ bb1,
    unsigned short* __restrict__ hs0,          // [T][B][1024] bf16
    unsigned short* __restrict__ hs1,
    unsigned long long* __restrict__ hbuf64,   // [2 par][2 d][64][512] bf16 as u64
    unsigned int* __restrict__ flags)          // [2 l][2 d][256] + [1024] layer
{
    __shared__ int   tok_s[64];
    __shared__ float Gred[4][64][17];
    __shared__ float hsh[64][4];

    const int bid = blockIdx.x;
    const int d   = bid >> 7;
    const int nt  = bid & 127;
    const int tid = threadIdx.x;
    const int w    = tid >> 6;
    const int lane = tid & 63;
    const int lm = lane & 15, q = lane >> 4;
    const int gm = tid >> 2, gj = tid & 3;     // gate-phase cell (batch, hcol-off)

    bool dead = false;
    float creg = 0.0f;

    for (int l = 0; l < 2; ++l) {
        const int xK  = l ? 1024 : 512;
        const int xKt = xK >> 5;
        const int KT  = xKt + 16;
        const int nX  = xKt >> 2;              // X-phase kts per wave
        const unsigned short* wp = (l ? wp1 : wp0) + ((long long)(d * 128 + nt)) * KT * 512;
        const float* bia = (l ? bb1 : bb0) + (long long)d * 2048;
        unsigned short* hso = l ? hs1 : hs0;
        unsigned int* flagp = flags + (l * 2 + d) * 256;

        float breg[4];
        #pragma unroll
        for (int g = 0; g < 4; ++g) breg[g] = bia[g * 512 + nt * 4 + gj];
        creg = 0.0f;

        for (int s = 0; s < T_STEPS; ++s) {
            const int tt = d ? (T_STEPS - 1 - s) : s;

            f32x4 acc[4];
            #pragma unroll
            for (int mt = 0; mt < 4; ++mt) acc[mt] = (f32x4)0.0f;

            if (l == 0 && tid < 64) tok_s[tid] = tokens[tt * BATCH + tid];
            __syncthreads();

            // A-row base pointers for this step (lane-dependent row lm)
            const unsigned short* xr[4];
            #pragma unroll
            for (int mt = 0; mt < 4; ++mt) {
                int m = mt * 16 + lm;
                if (l == 0) xr[mt] = embB + (long long)tok_s[m] * 512;
                else        xr[mt] = hs0 + ((long long)tt * 64 + m) * 1024;
            }

            // ---------------- X phase (no h dependency) ---------------------
            for (int i = 0; i < nX; ++i) {
                const int kt = w * nX + i;
                V16 bv; bv.u = *(const uint4*)(wp + (long long)kt * 512 + lane * 8);
                #pragma unroll
                for (int mt = 0; mt < 4; ++mt) {
                    V16 av; av.u = *(const uint4*)(xr[mt] + kt * 32 + q * 8);
                    acc[mt] = __builtin_amdgcn_mfma_f32_16x16x32_bf16(av.s, bv.s, acc[mt], 0, 0, 0);
                }
            }

            // ---------------- wait h(s-1), recurrent phase ------------------
            if (s > 0) {
                if (tid == 0 && !dead) {
                    int n = 0;
                    while (__hip_atomic_load(flagp + (s - 1), __ATOMIC_RELAXED,
                                             __HIP_MEMORY_SCOPE_AGENT) < NBLK_DIR) {
                        __builtin_amdgcn_s_sleep(1);
                        if (++n > SPIN_LIM) { dead = true; break; }
                    }
                }
                __syncthreads();
                const unsigned long long* hb =
                    hbuf64 + ((long long)(((s - 1) & 1) * 2 + d) * 64 * 512) / 4;
                #pragma unroll
                for (int i = 0; i < 4; ++i) {
                    const int kth = w * 4 + i;
                    V16 bv; bv.u = *(const uint4*)(wp + (long long)(xKt + kth) * 512 + lane * 8);
                    #pragma unroll
                    for (int mt = 0; mt < 4; ++mt) {
                        int m = mt * 16 + lm;
                        long long o = ((long long)m * 512 + kth * 32 + q * 8) >> 2;
                        HQ h;
                        h.q[0] = __hip_atomic_load(hb + o,     __ATOMIC_RELAXED, __HIP_MEMORY_SCOPE_AGENT);
                        h.q[1] = __hip_atomic_load(hb + o + 1, __ATOMIC_RELAXED, __HIP_MEMORY_SCOPE_AGENT);
                        acc[mt] = __builtin_amdgcn_mfma_f32_16x16x32_bf16(h.s, bv.s, acc[mt], 0, 0, 0);
                    }
                }
            }

            // ---------------- K-reduce across waves + gates -----------------
            #pragma unroll
            for (int mt = 0; mt < 4; ++mt)
                #pragma unroll
                for (int r = 0; r < 4; ++r)
                    Gred[w][mt * 16 + q * 4 + r][lm] = acc[mt][r];
            __syncthreads();

            float vg[4];
            #pragma unroll
            for (int g = 0; g < 4; ++g) {
                float v = breg[g];
                #pragma unroll
                for (int ww = 0; ww < 4; ++ww) v += Gred[ww][gm][g * 4 + gj];
                vg[g] = v;
            }
            const float si = 1.0f / (1.0f + __expf(-vg[0]));
            const float sf = 1.0f / (1.0f + __expf(-vg[1]));
            const float so = 1.0f / (1.0f + __expf(-vg[3]));
            const float cn = sf * creg + si * tanhf(vg[2]);
            const float hn = so * tanhf(cn);
            creg = cn;
            hsh[gm][gj] = hn;
            __syncthreads();

            // ---------------- publish h (IF) + hs (cached) ------------------
            if (tid < 64) {
                const int b = tid;
                unsigned long long hv =
                      (unsigned long long)f2b(hsh[b][0])
                    | ((unsigned long long)f2b(hsh[b][1]) << 16)
                    | ((unsigned long long)f2b(hsh[b][2]) << 32)
                    | ((unsigned long long)f2b(hsh[b][3]) << 48);
                unsigned long long* dst =
                    hbuf64 + ((long long)((s & 1) * 2 + d) * 64 * 512 + (long long)b * 512 + nt * 4) / 4;
                __hip_atomic_store(dst, hv, __ATOMIC_RELAXED, __HIP_MEMORY_SCOPE_AGENT);
                *(unsigned long long*)(hso + ((long long)tt * 64 + b) * 1024 + d * 512 + nt * 4) = hv;
            }
            asm volatile("s_waitcnt vmcnt(0)" ::: "memory");
            __syncthreads();
            if (tid == 0)
                __hip_atomic_fetch_add(flagp + s, 1u, __ATOMIC_RELAXED, __HIP_MEMORY_SCOPE_AGENT);
        }

        // ------------- layer boundary: publish hs0 for cached L1 reads ------
        if (l == 0) {
            __threadfence();                    // wb dirty hs0 out of local L2
            __syncthreads();
            if (tid == 0) {
                __hip_atomic_fetch_add(flags + 1024, 1u, __ATOMIC_RELAXED, __HIP_MEMORY_SCOPE_AGENT);
                int n = 0;
                while (!dead && __hip_atomic_load(flags + 1024, __ATOMIC_RELAXED,
                                                  __HIP_MEMORY_SCOPE_AGENT) < NBLK) {
                    __builtin_amdgcn_s_sleep(1);
                    if (++n > SPIN_LIM) dead = true;
                }
            }
            __syncthreads();
            __threadfence();                    // inv stale lines (incl. prior replay)
        }
    }
}

// ---------------------------------------------------------------------------
// feats = hs1(bf16) @ lin_w^T + lin_b   (64-row tiles, N=32)
// ---------------------------------------------------------------------------
__global__ __launch_bounds__(256) void gemm_feats(
    const unsigned short* __restrict__ A,      // [M][1024] bf16
    const float* __restrict__ W,               // [32][1024]
    const float* __restrict__ bias,
    float* __restrict__ C,
    int M, int N, int K)
{
    __shared__ __align__(16) float As[64][34];
    __shared__ __align__(16) float Ws[32][68];

    const int m0 = blockIdx.y * 64;
    const int tid = threadIdx.x;
    const int tr = tid >> 4;
    const int tc = tid & 15;

    float acc[4][4];
    #pragma unroll
    for (int i = 0; i < 4; ++i)
        #pragma unroll
        for (int j = 0; j < 4; ++j) acc[i][j] = 0.0f;

    for (int k0 = 0; k0 < K; k0 += 32) {
        {   // A tile: 64 rows x 32 k (bf16 -> f32)
            int row = tid >> 2, g8 = tid & 3;
            uint4 v = *(const uint4*)(A + ((long long)(m0 + row)) * 1024 + k0 + g8 * 8);
            const unsigned short* pv = (const unsigned short*)&v;
            #pragma unroll
            for (int e = 0; e < 8; ++e) As[row][g8 * 8 + e] = b2f(pv[e]);
        }
        {   // W tile: 32 rows x 32 k, transposed
            int row = tid >> 3, q2 = tid & 7;
            float4 v = *(const float4*)(W + (long long)row * K + k0 + 4 * q2);
            Ws[4*q2+0][row] = v.x; Ws[4*q2+1][row] = v.y;
            Ws[4*q2+2][row] = v.z; Ws[4*q2+3][row] = v.w;
        }
        __syncthreads();
        #pragma unroll 8
        for (int kk = 0; kk < 32; ++kk) {
            float a0 = As[4*tr+0][kk], a1 = As[4*tr+1][kk];
            float a2 = As[4*tr+2][kk], a3 = As[4*tr+3][kk];
            float4 wv = *(const float4*)&Ws[kk][4*tc];
            acc[0][0] += a0*wv.x; acc[0][1] += a0*wv.y; acc[0][2] += a0*wv.z; acc[0][3] += a0*wv.w;
            acc[1][0] += a1*wv.x; acc[1][1] += a1*wv.y; acc[1][2] += a1*wv.z; acc[1][3] += a1*wv.w;
            acc[2][0] += a2*wv.x; acc[2][1] += a2*wv.y; acc[2][2] += a2*wv.z; acc[2][3] += a2*wv.w;
            acc[3][0] += a3*wv.x; acc[3][1] += a3*wv.y; acc[3][2] += a3*wv.z; acc[3][3] += a3*wv.w;
        }
        __syncthreads();
    }
    #pragma unroll
    for (int i = 0; i < 4; ++i) {
        int m = m0 + 4*tr + i;
        #pragma unroll
        for (int j = 0; j < 4; ++j) {
            int n = 4*tc + j;
            if (n < N) C[(long long)m * N + n] = acc[i][j] + bias[n];
        }
    }
}

// ---------------------------------------------------------------------------
// CRF: forward logsumexp scan + log_z + gold score + loss, one block per b.
// ---------------------------------------------------------------------------
__global__ __launch_bounds__(1024) void crf_kernel(
    const float* __restrict__ feats,
    const float* __restrict__ trans,
    const int*   __restrict__ tokens,
    const int*   __restrict__ tags,
    const int*   __restrict__ lengths,
    float* __restrict__ out)
{
    const int b = blockIdx.x;
    const int tid = threadIdx.x;
    __shared__ float tr_s[KTAGS*KTAGS];
    __shared__ float score_s[KTAGS];
    __shared__ float emit_s[KTAGS];
    __shared__ float red_s[16];
    __shared__ float logz_s;

    tr_s[tid] = trans[tid];
    if (tid < KTAGS) score_s[tid] = (tid == START_TAG) ? 0.0f : NEGV;
    __syncthreads();

    const int i = tid >> 5, j = tid & 31;
    for (int t = 0; t < T_STEPS; ++t) {
        if (tid < KTAGS) emit_s[tid] = feats[((long long)t*BATCH + b)*KTAGS + tid];
        __syncthreads();
        float e = score_s[j] + tr_s[i*KTAGS + j];
        float m = e;
        m = fmaxf(m, __shfl_xor(m, 1));  m = fmaxf(m, __shfl_xor(m, 2));
        m = fmaxf(m, __shfl_xor(m, 4));  m = fmaxf(m, __shfl_xor(m, 8));
        m = fmaxf(m, __shfl_xor(m, 16));
        float p = __expf(e - m);
        p += __shfl_xor(p, 1); p += __shfl_xor(p, 2); p += __shfl_xor(p, 4);
        p += __shfl_xor(p, 8); p += __shfl_xor(p, 16);
        float nv = m + __logf(p) + emit_s[i];
        int msk = tokens[(long long)t*BATCH + b] > 0;
        __syncthreads();
        if (j == 0) score_s[i] = msk ? nv : score_s[i];
        __syncthreads();
    }

    if (tid < KTAGS) {
        float v = score_s[tid] + tr_s[END_TAG*KTAGS + tid];
        float m = v;
        m = fmaxf(m, __shfl_xor(m, 1));  m = fmaxf(m, __shfl_xor(m, 2));
        m = fmaxf(m, __shfl_xor(m, 4));  m = fmaxf(m, __shfl_xor(m, 8));
        m = fmaxf(m, __shfl_xor(m, 16));
        float p = __expf(v - m);
        p += __shfl_xor(p, 1); p += __shfl_xor(p, 2); p += __shfl_xor(p, 4);
        p += __shfl_xor(p, 8); p += __shfl_xor(p, 16);
        if (tid == 0) logz_s = m + __logf(p);
    }
    __syncthreads();

    float val = 0.0f;
    if (tid < T_STEPS) {
        int t = tid;
        int cur  = tags[(long long)t*BATCH + b];
        int prev = (t == 0) ? START_TAG : tags[(long long)(t-1)*BATCH + b];
        int msk  = tokens[(long long)t*BATCH + b] > 0;
        if (msk) val = tr_s[cur*KTAGS + prev]
                     + feats[((long long)t*BATCH + b)*KTAGS + cur];
    }
    val += __shfl_xor(val, 1);  val += __shfl_xor(val, 2);
    val += __shfl_xor(val, 4);  val += __shfl_xor(val, 8);
    val += __shfl_xor(val, 16); val += __shfl_xor(val, 32);
    int wave = tid >> 6, lane = tid & 63;
    if (lane == 0) red_s[wave] = val;
    __syncthreads();
    if (tid == 0) {
        float g = 0.0f;
        #pragma unroll
        for (int w = 0; w < 16; ++w) g += red_s[w];
        g += tr_s[END_TAG*KTAGS + tags[(long long)(T_STEPS-1)*BATCH + b]];
        atomicAdd(out, (logz_s - g) / (float)lengths[b]);
    }
}

// ---------------------------------------------------------------------------
extern "C" void kernel_launch(void* const* d_in, const int* in_sizes, int n_in,
                              void* d_out, int out_size, void* d_ws, size_t ws_size,
                              hipStream_t stream) {
    const int*   tokens  = (const int*)  d_in[0];
    const int*   tags    = (const int*)  d_in[1];
    const int*   lengths = (const int*)  d_in[2];
    const float* embed   = (const float*)d_in[3];
    const float* wih0    = (const float*)d_in[4];
    const float* whh0    = (const float*)d_in[5];
    const float* b0      = (const float*)d_in[6];
    const float* wih1    = (const float*)d_in[7];
    const float* whh1    = (const float*)d_in[8];
    const float* b1      = (const float*)d_in[9];
    const float* lin_w   = (const float*)d_in[10];
    const float* lin_b   = (const float*)d_in[11];
    const float* trans   = (const float*)d_in[12];

    // Workspace layout (total ~123.2 MiB)
    char* ws = (char*)d_ws;
    unsigned short* hs0   = (unsigned short*)(ws);                   // 33,554,432
    unsigned short* hs1   = (unsigned short*)(ws +  33554432ULL);    // 33,554,432
    unsigned short* embB  = (unsigned short*)(ws +  67108864ULL);    // 32,768,000
    unsigned short* wp0   = (unsigned short*)(ws +  99876864ULL);    //  8,388,608
    unsigned short* wp1   = (unsigned short*)(ws + 108265472ULL);    // 12,582,912
    float*          feats = (float*)        (ws + 120848384ULL);     //  2,097,152
    unsigned long long* hbuf = (unsigned long long*)(ws + 122945536ULL); // 262,144
    unsigned int*   flags = (unsigned int*) (ws + 123207680ULL);     //  4,096

    float* out = (float*)d_out;

    init_zero<<<dim3(5), 256, 0, stream>>>(flags, out);
    convert_embed<<<dim3(16000), 256, 0, stream>>>(embed, embB);
    pack_w<<<dim3(2048), 256, 0, stream>>>(wih0, whh0, 512,  wp0);
    pack_w<<<dim3(3072), 256, 0, stream>>>(wih1, whh1, 1024, wp1);

    lstm_mfma<<<dim3(NBLK), 256, 0, stream>>>(
        tokens, embB, wp0, wp1, b0, b1, hs0, hs1, hbuf, flags);

    gemm_feats<<<dim3(1, 256, 1), 256, 0, stream>>>(
        hs1, lin_w, lin_b, feats, T_STEPS*BATCH, KTAGS, 2*HID);

    crf_kernel<<<dim3(BATCH), 1024, 0, stream>>>(feats, trans, tokens, tags,
                                                 lengths, out);
}